// Round 19
// baseline (32.011 us; speedup 1.0000x reference)
//
#include <hip/hip_runtime.h>

#define C 128
#define NPIX 16384      // 4 * 64 * 64
#define THREE_C 384

typedef unsigned short u16;
typedef unsigned int u32;
typedef short bf16x8 __attribute__((ext_vector_type(8)));
typedef float f32x4 __attribute__((ext_vector_type(4)));

__device__ __forceinline__ float bf2f(u16 h) { return __uint_as_float(((u32)h) << 16); }
__device__ __forceinline__ u16 f2bf(float f) {
    u32 b = __float_as_uint(f);
    b += 0x7FFF + ((b >> 16) & 1);          // RNE
    return (u16)(b >> 16);
}
__device__ __forceinline__ u32 pack2(float a, float b) {
    return (u32)f2bf(a) | ((u32)f2bf(b) << 16);
}

// ---------------- Kernel 1: qkv = x @ W_qkv via MFMA (M=16384, N=384, K=128) ----------------
// 64-row tiles. Grid 768 -> 3 blocks/CU. 256 thr = 4 waves x 16-row strips.  (R18 version.)
#define GST 136

__global__ __launch_bounds__(256) void qkv_kernel(const float* __restrict__ x,
                                                  const float* __restrict__ Wqkv,
                                                  const float* __restrict__ Wwidth,
                                                  const float* __restrict__ bwidth,
                                                  const float* __restrict__ Wout,
                                                  u16* __restrict__ qb,
                                                  u16* __restrict__ kb,
                                                  u16* __restrict__ vb,
                                                  float* __restrict__ width_g,
                                                  u16* __restrict__ wot) {
    __shared__ u16 xs[64 * GST];    // 17408 B
    __shared__ u16 wt[128 * GST];   // 34816 B
    const int task = ((int)(blockIdx.x & 7)) * 96 + ((int)blockIdx.x >> 3);
    const int rb = task / 3;
    const int nb = task % 3;
    const int p0 = rb * 64;
    const int tid = threadIdx.x;
    const int wv = tid >> 6;
    const int l = tid & 63;
    const int l15 = l & 15;
    const int l4 = l >> 4;

#pragma unroll
    for (int t = 0; t < 8; ++t) {
        const int f = tid + t * 256;
        const int kq = f & 31, r = f >> 5;
        const float4 xv = *(const float4*)(x + (size_t)(p0 + r) * C + kq * 4);
        uint2 pk;
        pk.x = pack2(xv.x, xv.y);
        pk.y = pack2(xv.z, xv.w);
        *(uint2*)&xs[r * GST + kq * 4] = pk;
    }
#pragma unroll
    for (int t = 0; t < 16; ++t) {
        const int f = tid + t * 256;
        const int c = f & 127, kq = f >> 7;
        const float w0 = Wqkv[(size_t)(kq * 4 + 0) * THREE_C + nb * 128 + c];
        const float w1 = Wqkv[(size_t)(kq * 4 + 1) * THREE_C + nb * 128 + c];
        const float w2 = Wqkv[(size_t)(kq * 4 + 2) * THREE_C + nb * 128 + c];
        const float w3 = Wqkv[(size_t)(kq * 4 + 3) * THREE_C + nb * 128 + c];
        uint2 pk;
        pk.x = pack2(w0, w1);
        pk.y = pack2(w2, w3);
        *(uint2*)&wt[c * GST + kq * 4] = pk;
    }
    // W_out^T precompute: wot[c*128 + k] = bf16(Wout[k][c]); 8 blocks x 256 thr x 8 u16.
    if (task < 8) {
        const int base = (task * 256 + tid) * 8;
        const int c = base >> 7, k0 = base & 127;
        uint4 pk;
        pk.x = pack2(Wout[(size_t)(k0 + 0) * C + c], Wout[(size_t)(k0 + 1) * C + c]);
        pk.y = pack2(Wout[(size_t)(k0 + 2) * C + c], Wout[(size_t)(k0 + 3) * C + c]);
        pk.z = pack2(Wout[(size_t)(k0 + 4) * C + c], Wout[(size_t)(k0 + 5) * C + c]);
        pk.w = pack2(Wout[(size_t)(k0 + 6) * C + c], Wout[(size_t)(k0 + 7) * C + c]);
        *(uint4*)&wot[base] = pk;
    }
    __syncthreads();

    if (nb == 0 && tid < 64) {
        float wacc = 0.f;
#pragma unroll
        for (int kk = 0; kk < C; ++kk) wacc += bf2f(xs[tid * GST + kk]) * Wwidth[kk];
        const float z = wacc + bwidth[0];
        width_g[p0 + tid] = (1.f / (1.f + __expf(-z))) * 4.242640687f + 0.5f;
    }

    const int strip = wv * 16;
    bf16x8 af[4];
#pragma unroll
    for (int kf = 0; kf < 4; ++kf)
        af[kf] = *(const bf16x8*)&xs[(strip + l15) * GST + kf * 32 + l4 * 8];

    f32x4 acc[8];
#pragma unroll
    for (int nf = 0; nf < 8; ++nf) acc[nf] = (f32x4){0.f, 0.f, 0.f, 0.f};
#pragma unroll
    for (int nf = 0; nf < 8; ++nf) {
#pragma unroll
        for (int kf = 0; kf < 4; ++kf) {
            const bf16x8 bf = *(const bf16x8*)&wt[(nf * 16 + l15) * GST + kf * 32 + l4 * 8];
            acc[nf] = __builtin_amdgcn_mfma_f32_16x16x32_bf16(af[kf], bf, acc[nf], 0, 0, 0);
        }
    }

    u16* dst = (nb == 0) ? qb : (nb == 1) ? kb : vb;
#pragma unroll
    for (int nf = 0; nf < 8; ++nf) {
        const int col = nf * 16 + l15;
#pragma unroll
        for (int r = 0; r < 4; ++r) {
            const int row = strip + l4 * 4 + r;
            dst[(size_t)(p0 + row) * C + col] = f2bf(acc[nf][r]);
        }
    }
}

// ---------------- Kernel 2: fused attention + output projection, 4x4 tiles ----------------
// 1024 blocks x 512 thr (8 waves). Halo 10x10=100 -> rows padded 112 (7 frags); PV-K 128.
// LDS ~70KB -> 2 blocks/CU (the point of this round). Stride 136 everywhere (<=2-way banks).
// NO-MAX softmax; P unnormalized; norm in PV epilogue. W_out^T read direct from global wot.
// Barriers: B1(stage) -> B2(P+sums) -> B3(y).  Kl rows 0-15 reused for y after B2.
#define HST 136

__global__ __launch_bounds__(512, 4) void attn_kernel(const u16* __restrict__ qb,
                                                      const u16* __restrict__ kb,
                                                      const u16* __restrict__ vb,
                                                      const float* __restrict__ width_g,
                                                      const u16* __restrict__ wot,
                                                      float* __restrict__ out) {
    __shared__ u16 Kl[112 * HST];   // 30464 B
    __shared__ u16 Vt[128 * HST];   // 34816 B  [channel][halo k 0..127]
    __shared__ u16 Pl[16 * HST];    // 4352 B   [qrow][halo n 0..127]
    __shared__ float rsum[7][16];
    __shared__ float wdl[16];

    const int tid = threadIdx.x;
    const int wv = tid >> 6;            // 0..7
    const int l = tid & 63;
    const int l15 = l & 15;
    const int l4 = l >> 4;

    const int W = ((int)(blockIdx.x & 7) << 7) + ((int)blockIdx.x >> 3);  // XCD-chunked
    const int b = W >> 8;
    const int t = W & 255;
    const int i0 = (t >> 4) * 4;
    const int j0 = (t & 15) * 4;
    const int pbase = b * 4096;

    if (tid < 16)
        wdl[tid] = width_g[pbase + (i0 + (tid >> 2)) * 64 + j0 + (tid & 3)];

    // ======== staging: issue ALL global loads, then LDS writes ========
    const uint4 z4 = make_uint4(0, 0, 0, 0);
    // K: 112 rows x 16 octets = 1792 tasks (rr=0..2 full, rr=3 tid<256)
    uint4 kreg[4];
    int koff[4];
    bool kw[4];
#pragma unroll
    for (int rr = 0; rr < 4; ++rr) {
        const int f = tid + rr * 512;
        kw[rr] = (f < 1792);
        kreg[rr] = z4;
        const int c = f & 15, h = f >> 4;
        koff[rr] = h * HST + c * 8;
        if (kw[rr] && h < 100) {
            const int hi = (h * 3277) >> 15;          // h / 10
            const int hj = h - hi * 10;
            const int ii = i0 - 3 + hi, jj = j0 - 3 + hj;
            if (((unsigned)ii < 64u) && ((unsigned)jj < 64u))
                kreg[rr] = *(const uint4*)(kb + (size_t)(pbase + ii * 64 + jj) * C + c * 8);
        }
    }
    // V: 56 h-pairs x 16 octets = 896 tasks (rr=0 full, rr=1 tid<384; tail threads zero cols 112-127)
    uint4 va[2], vz[2];
    int vc8[2], vh[2];
    bool vw[2];
#pragma unroll
    for (int rr = 0; rr < 2; ++rr) {
        const int f = tid + rr * 512;
        vw[rr] = (f < 896);
        va[rr] = z4; vz[rr] = z4;
        const int c8 = f & 15, h = ((f >> 4) * 2) & 127;
        vc8[rr] = c8; vh[rr] = h;
        if (vw[rr]) {
            {
                const int hi = (h * 3277) >> 15;
                const int hj = h - hi * 10;
                const int ii = i0 - 3 + hi, jj = j0 - 3 + hj;
                if ((h < 100) && ((unsigned)ii < 64u) && ((unsigned)jj < 64u))
                    va[rr] = *(const uint4*)(vb + (size_t)(pbase + ii * 64 + jj) * C + c8 * 8);
            }
            {
                const int h1 = h + 1;
                const int hi = (h1 * 3277) >> 15;
                const int hj = h1 - hi * 10;
                const int ii = i0 - 3 + hi, jj = j0 - 3 + hj;
                if ((h1 < 100) && ((unsigned)ii < 64u) && ((unsigned)jj < 64u))
                    vz[rr] = *(const uint4*)(vb + (size_t)(pbase + ii * 64 + jj) * C + c8 * 8);
            }
        }
    }
    // Q A-fragments direct from global (own 16 rows)
    bf16x8 qf[4];
    {
        const int qr = l15;
        const int p = pbase + (i0 + (qr >> 2)) * 64 + j0 + (qr & 3);
#pragma unroll
        for (int kf = 0; kf < 4; ++kf)
            qf[kf] = *(const bf16x8*)(qb + (size_t)p * C + kf * 32 + l4 * 8);
    }
    // ---- LDS writes ----
#pragma unroll
    for (int rr = 0; rr < 4; ++rr)
        if (kw[rr]) *(uint4*)&Kl[koff[rr]] = kreg[rr];
#pragma unroll
    for (int rr = 0; rr < 2; ++rr) {
        if (vw[rr]) {
            union { uint4 u4; u16 us[8]; } ua, uz;
            ua.u4 = va[rr]; uz.u4 = vz[rr];
            const int c8 = vc8[rr], h = vh[rr];
#pragma unroll
            for (int s = 0; s < 8; ++s) {
                const int ch = c8 * 8 + s;
                *(u32*)&Vt[ch * HST + h] = (u32)ua.us[s] | ((u32)uz.us[s] << 16);
            }
        }
    }
    // zero Vt halo cols 112..127 (PV K-pad; P is zero there but avoid NaN*0)
    {
        const int f = tid + 512;
        if (f >= 896) {
            const int ch = f - 896;   // 0..127
#pragma unroll
            for (int s = 0; s < 8; ++s)
                *(u32*)&Vt[ch * HST + 112 + s * 2] = 0u;
        }
    }
    __syncthreads();  // B1: staged

    // ---- QK^T: wave g handles nf = g (halo cols g*16..g*16+15), g<7 ----
    const int g = wv;
    f32x4 sv = {0.f, 0.f, 0.f, 0.f};
    if (g < 7) {
        const u16* kr = Kl + (g * 16 + l15) * HST + l4 * 8;
#pragma unroll
        for (int kf = 0; kf < 4; ++kf)
            sv = __builtin_amdgcn_mfma_f32_16x16x32_bf16(
                qf[kf], *(const bf16x8*)(kr + kf * 32), sv, 0, 0, 0);
    }

    // issue W_out^T B-fragments direct from global (L2-hot); used after B3
    bf16x8 wof[4];
#pragma unroll
    for (int kf = 0; kf < 4; ++kf)
        wof[kf] = *(const bf16x8*)(wot + (size_t)(g * 16 + l15) * 128 + kf * 32 + l4 * 8);

    // ---- mask + penalty + direct exp + sums + P write ----
    const int qrb = l4 * 4;
    float wdr[4];
#pragma unroll
    for (int r = 0; r < 4; ++r) wdr[r] = wdl[qrb + r];
    if (g < 7) {
        const int n = g * 16 + l15;
        float smr[4];
        int hi = 0, hj = 0;
        const bool ncol = (n < 100);
        if (ncol) { hi = (n * 3277) >> 15; hj = n - hi * 10; }
#pragma unroll
        for (int r = 0; r < 4; ++r) {
            const int row = qrb + r;
            float e = 0.f;
            if (ncol) {
                const int di = hi - 3 - (row >> 2);
                const int dj = hj - 3 - (row & 3);
                if (((unsigned)(di + 3) <= 6u) && ((unsigned)(dj + 3) <= 6u)) {
                    const float rd = sqrtf((float)(di * di + dj * dj));
                    const float sm = 1.f / (1.f + __expf(-5.f * (wdr[r] - rd)));
                    e = __expf(sv[r] * 0.08838834765f - (1.f - sm) * 10000.f);
                }
            }
            smr[r] = e;
            Pl[row * HST + n] = f2bf(e);
        }
#pragma unroll
        for (int r = 0; r < 4; ++r) {
            float s = smr[r];
            s += __shfl_xor(s, 1);
            s += __shfl_xor(s, 2);
            s += __shfl_xor(s, 4);
            s += __shfl_xor(s, 8);
            if (l15 == 0) rsum[g][qrb + r] = s;
        }
    } else {
        // wave 7: zero P pad cols 112..127
#pragma unroll
        for (int r = 0; r < 4; ++r)
            Pl[(qrb + r) * HST + 112 + l15] = 0;
    }
    __syncthreads();  // B2: P + sums ready; Kl reads done

    float invr[4];
#pragma unroll
    for (int r = 0; r < 4; ++r) {
        const int row = qrb + r;
        invr[r] = 1.f / (rsum[0][row] + rsum[1][row] + rsum[2][row] + rsum[3][row]
                       + rsum[4][row] + rsum[5][row] + rsum[6][row]);
    }

    // ---- PV: O_u = P_u @ V (K=128); wave g -> channels g*16..g*16+15 ----
    f32x4 oacc = {0.f, 0.f, 0.f, 0.f};
#pragma unroll
    for (int kf = 0; kf < 4; ++kf) {
        const bf16x8 pa = *(const bf16x8*)(Pl + l15 * HST + kf * 32 + l4 * 8);
        const bf16x8 vf = *(const bf16x8*)(Vt + (g * 16 + l15) * HST + kf * 32 + l4 * 8);
        oacc = __builtin_amdgcn_mfma_f32_16x16x32_bf16(pa, vf, oacc, 0, 0, 0);
    }

    // ---- y = O_u*inv + v_own (bf16) into Kl rows 0-15 (dead) ----
    u16* YL = Kl;
    {
        const int ch = g * 16 + l15;
#pragma unroll
        for (int r = 0; r < 4; ++r) {
            const int row = qrb + r;
            const int hown = 33 + (row >> 2) * 10 + (row & 3);
            const float vv = bf2f(Vt[ch * HST + hown]);
            YL[row * HST + ch] = f2bf(oacc[r] * invr[r] + vv);
        }
    }
    __syncthreads();  // B3: y ready

    // ---- output projection: out = y @ W_out (B-frags from global, preloaded) ----
    f32x4 oc = {0.f, 0.f, 0.f, 0.f};
#pragma unroll
    for (int kf = 0; kf < 4; ++kf) {
        const bf16x8 yf = *(const bf16x8*)(YL + l15 * HST + kf * 32 + l4 * 8);
        oc = __builtin_amdgcn_mfma_f32_16x16x32_bf16(yf, wof[kf], oc, 0, 0, 0);
    }
    {
        const int col = g * 16 + l15;
#pragma unroll
        for (int r = 0; r < 4; ++r) {
            const int row = qrb + r;
            const int p = pbase + (i0 + (row >> 2)) * 64 + j0 + (row & 3);
            out[(size_t)p * C + col] = oc[r];
        }
    }
}

extern "C" void kernel_launch(void* const* d_in, const int* in_sizes, int n_in,
                              void* d_out, int out_size, void* d_ws, size_t ws_size,
                              hipStream_t stream) {
    const float* x      = (const float*)d_in[0];
    const float* Wqkv   = (const float*)d_in[1];
    const float* Wwidth = (const float*)d_in[2];
    const float* bwidth = (const float*)d_in[3];
    const float* Wout   = (const float*)d_in[4];
    float* out = (float*)d_out;

    u16* qb = (u16*)d_ws;                           // 4 MB bf16
    u16* kb = qb + (size_t)NPIX * C;                // 4 MB bf16
    u16* vb = kb + (size_t)NPIX * C;                // 4 MB bf16
    float* width = (float*)(vb + (size_t)NPIX * C); // 64 KB fp32
    u16* wot = (u16*)(width + NPIX);                // 32 KB bf16 W_out^T

    qkv_kernel<<<768, 256, 0, stream>>>(x, Wqkv, Wwidth, bwidth, Wout, qb, kb, vb, width, wot);
    attn_kernel<<<1024, 512, 0, stream>>>(qb, kb, vb, width, wot, out);
}